// Round 2
// baseline (687.402 us; speedup 1.0000x reference)
//
#include <hip/hip_runtime.h>

#define C_S 384
#define C_Z 128
#define N_SEQ 1024

// Kernel 1: per-row projections si[n] = dot(s[n], Wi), sj[n] = dot(s[n], Wj) + b.
// One wave per row n. 4 waves per 256-thread block -> 256 blocks. ~Âµs-scale.
__global__ __launch_bounds__(256) void sisj_kernel(const float* __restrict__ s,
                                                   const float* __restrict__ W,
                                                   const float* __restrict__ b,
                                                   float* __restrict__ si,
                                                   float* __restrict__ sj) {
    const int lane = threadIdx.x & 63;
    const int wave = threadIdx.x >> 6;
    const int n = blockIdx.x * 4 + wave;

    const float* srow = s + (size_t)n * C_S;
    const float* Wi = W;          // W[0, 0:384]
    const float* Wj = W + C_S;    // W[0, 384:768]

    float acc_i = 0.f, acc_j = 0.f;
#pragma unroll
    for (int j = 0; j < C_S / 64; ++j) {
        const int idx = lane + 64 * j;
        const float v = srow[idx];
        acc_i += v * Wi[idx];
        acc_j += v * Wj[idx];
    }
#pragma unroll
    for (int mask = 32; mask >= 1; mask >>= 1) {
        acc_i += __shfl_xor(acc_i, mask);
        acc_j += __shfl_xor(acc_j, mask);
    }
    if (lane == 0) {
        si[n] = acc_i;
        sj[n] = acc_j + b[0];
    }
}

// Kernel 2: one OUTPUT per THREAD (row-per-lane GEMV).
// Lane l streams its own 512B z-row as 32 dwordx4 loads (unroll 8 -> 8 loads
// in flight), accumulates privately -> no shuffles, no LDS, no block churn.
// Lanes own consecutive rows; each lane's 4 successive float4s hit one 64B
// line, so all fetched lines are fully consumed. Wz is wave-uniform (s_load).
__global__ __launch_bounds__(256) void contact_kernel(const float* __restrict__ z,
                                                      const float* __restrict__ W,
                                                      const float* __restrict__ si,
                                                      const float* __restrict__ sj,
                                                      float* __restrict__ out) {
    const int o = blockIdx.x * 256 + threadIdx.x;          // flat output index
    const float4* __restrict__ zr = (const float4*)(z + ((size_t)o << 7));
    const float4* __restrict__ wz = (const float4*)(W + 2 * C_S);

    float4 acc = make_float4(0.f, 0.f, 0.f, 0.f);
#pragma unroll 8
    for (int k = 0; k < C_Z / 4; ++k) {
        const float4 a = zr[k];
        const float4 w = wz[k];
        acc.x += a.x * w.x;
        acc.y += a.y * w.y;
        acc.z += a.z * w.z;
        acc.w += a.w * w.w;
    }
    const float p = (acc.x + acc.y) + (acc.z + acc.w);
    out[o] = p + si[o >> 10] + sj[o & 1023];
}

extern "C" void kernel_launch(void* const* d_in, const int* in_sizes, int n_in,
                              void* d_out, int out_size, void* d_ws, size_t ws_size,
                              hipStream_t stream) {
    const float* s = (const float*)d_in[0];   // (1,1024,384)
    const float* z = (const float*)d_in[1];   // (1,1024,1024,128)
    const float* W = (const float*)d_in[2];   // (1,896)
    const float* b = (const float*)d_in[3];   // (1,)
    float* out = (float*)d_out;               // (1,1024,1024,1)

    float* si = (float*)d_ws;                 // 1024 floats
    float* sj = si + N_SEQ;                   // 1024 floats

    // 1024 rows, one wave each, 4 waves/block
    sisj_kernel<<<N_SEQ / 4, 256, 0, stream>>>(s, W, b, si, sj);

    // 1024*1024 outputs, 1 per thread, 256 threads/block -> 4096 blocks
    contact_kernel<<<(N_SEQ * N_SEQ) / 256, 256, 0, stream>>>(z, W, si, sj, out);
}

// Round 3
// 687.325 us; speedup vs baseline: 1.0001x; 1.0001x over previous
//
#include <hip/hip_runtime.h>

#define C_S 384
#define C_Z 128
#define N_SEQ 1024

// Kernel 1: per-row projections si[n] = dot(s[n], Wi), sj[n] = dot(s[n], Wj) + b.
// One wave per row n. 4 waves per 256-thread block -> 256 blocks. ~us-scale.
__global__ __launch_bounds__(256) void sisj_kernel(const float* __restrict__ s,
                                                   const float* __restrict__ W,
                                                   const float* __restrict__ b,
                                                   float* __restrict__ si,
                                                   float* __restrict__ sj) {
    const int lane = threadIdx.x & 63;
    const int wave = threadIdx.x >> 6;
    const int n = blockIdx.x * 4 + wave;

    const float* srow = s + (size_t)n * C_S;
    const float* Wi = W;          // W[0, 0:384]
    const float* Wj = W + C_S;    // W[0, 384:768]

    float acc_i = 0.f, acc_j = 0.f;
#pragma unroll
    for (int j = 0; j < C_S / 64; ++j) {
        const int idx = lane + 64 * j;
        const float v = srow[idx];
        acc_i += v * Wi[idx];
        acc_j += v * Wj[idx];
    }
#pragma unroll
    for (int mask = 32; mask >= 1; mask >>= 1) {
        acc_i += __shfl_xor(acc_i, mask);
        acc_j += __shfl_xor(acc_j, mask);
    }
    if (lane == 0) {
        si[n] = acc_i;
        sj[n] = acc_j + b[0];
    }
}

// Kernel 2: grid-stride, software-pipelined, fully-coalesced contact head.
// Each wave computes 2 outputs per iteration (lanes 0-31 -> output o, lanes
// 32-63 -> o+1); one dwordx4 per wave per iter covers a contiguous 1 KB of z.
// ITER=64 iterations per wave (contiguous 64 KB stream) with a 1-deep prefetch
// so the next load is in flight during the 5-step shuffle reduce.
#define ITER 64
__global__ __launch_bounds__(256) void contact_kernel(const float* __restrict__ z,
                                                      const float* __restrict__ W,
                                                      const float* __restrict__ si,
                                                      const float* __restrict__ sj,
                                                      float* __restrict__ out) {
    const int lane = threadIdx.x & 63;
    const int wave = threadIdx.x >> 6;
    const int half = lane >> 5;        // which of the 2 outputs in this iter
    const int l = lane & 31;           // position within the 32-lane group

    const int gw = blockIdx.x * 4 + wave;          // global wave id, 0..8191
    const size_t o0 = (size_t)gw * (2 * ITER);     // first output index for this wave

    // Wz fragment for this lane's channel slice (uniform across waves, L2-hot)
    const float4 wz = *(const float4*)(W + 2 * C_S + 4 * l);

    // z address for iter t: rows (o0+2t, o0+2t+1); half*128 + 4*l == 4*lane
    const float* zp = z + (o0 << 7) + (lane << 2);

    float4 cur = *(const float4*)zp;               // prefetch iter 0
#pragma unroll 4
    for (int t = 0; t < ITER; ++t) {
        float4 nxt;
        if (t + 1 < ITER) {
            nxt = *(const float4*)(zp + 256);      // issue next load before reduce
        }
        float p = cur.x * wz.x + cur.y * wz.y + cur.z * wz.z + cur.w * wz.w;
#pragma unroll
        for (int mask = 16; mask >= 1; mask >>= 1) {
            p += __shfl_xor(p, mask);              // stays within 32-lane half
        }
        if (l == 0) {
            const size_t o = o0 + 2 * t + half;
            out[o] = p + si[o >> 10] + sj[o & 1023];
        }
        cur = nxt;
        zp += 256;
    }
}

extern "C" void kernel_launch(void* const* d_in, const int* in_sizes, int n_in,
                              void* d_out, int out_size, void* d_ws, size_t ws_size,
                              hipStream_t stream) {
    const float* s = (const float*)d_in[0];   // (1,1024,384)
    const float* z = (const float*)d_in[1];   // (1,1024,1024,128)
    const float* W = (const float*)d_in[2];   // (1,896)
    const float* b = (const float*)d_in[3];   // (1,)
    float* out = (float*)d_out;               // (1,1024,1024,1)

    float* si = (float*)d_ws;                 // 1024 floats
    float* sj = si + N_SEQ;                   // 1024 floats

    sisj_kernel<<<N_SEQ / 4, 256, 0, stream>>>(s, W, b, si, sj);

    // 1M outputs = 2048 blocks x 4 waves x 2 outputs x 64 iters
    const int blocks = (N_SEQ * N_SEQ) / (2 * 4 * ITER);
    contact_kernel<<<blocks, 256, 0, stream>>>(z, W, si, sj, out);
}